// Round 12
// baseline (148.074 us; speedup 1.0000x reference)
//
#include <hip/hip_runtime.h>
#include <math.h>

typedef int i32x4 __attribute__((ext_vector_type(4)));
typedef int i32x16 __attribute__((ext_vector_type(16)));

#define CC 248
#define MM 65536
#define NN 1024

__device__ __forceinline__ float fexp2(float x) { return __builtin_amdgcn_exp2f(x); }

// ws: A_tiled [2][256 tiles][pl 2][kg 16][row 256][16]   = 67,108,864 B
//     B_tiled [2][32 ntiles][pl 2][kg 16][col 32][16]    =  1,048,576 B
//     partials [2][1024][64 mchunk] float4                =  2,097,152 B

// ---------------- convB: pixel descriptors -> i8 hi/lo planes, tiled ----------------
__global__ __launch_bounds__(512)
void convB_kernel(const float* __restrict__ dense, char* __restrict__ Ag) {
    __shared__ char at[2][16][128][16];       // 64 KB
    __shared__ float scr[4][128];
    const int bid = blockIdx.x;               // 0..1023
    const int fb  = bid >> 9;                 // 0..1 -> frame 2*fb
    const int p0  = (bid & 511) * 128;
    const int tid = threadIdx.x;
    const int row = tid & 127;
    const int q   = tid >> 7;                 // 0..3 -> channels q*64..q*64+63

    const float* dptr = dense + (size_t)(2 * fb) * CC * MM + p0 + row;
    float v[64];
    float ss = 0.f;
#pragma unroll
    for (int i = 0; i < 64; ++i) {
        int c = q * 64 + i;
        float x = (c < CC) ? dptr[(size_t)c * MM] : 0.f;
        v[i] = x;
        ss += x * x;
    }
    scr[q][row] = ss;
    __syncthreads();
    float inv = 32768.0f / fmaxf(sqrtf(scr[0][row] + scr[1][row] + scr[2][row] + scr[3][row]), 1e-12f);

#pragma unroll
    for (int j = 0; j < 16; ++j) {
        unsigned w1 = 0, w0 = 0;
#pragma unroll
        for (int t = 0; t < 4; ++t) {
            float qv = fminf(fmaxf(rintf(v[j * 4 + t] * inv), -32768.f), 32639.f);
            int af = (int)qv;
            int a1 = (af + 128) >> 8;
            int a0 = af - (a1 << 8);
            w1 |= (unsigned)(a1 & 255) << (8 * t);
            w0 |= (unsigned)(a0 & 255) << (8 * t);
        }
        int c0 = q * 64 + j * 4;
        int kg = c0 >> 4, dw = (c0 >> 2) & 3;
        *(unsigned*)&at[0][kg][row][dw * 4] = w1;
        *(unsigned*)&at[1][kg][row][dw * 4] = w0;
    }
    __syncthreads();

    const int tile = p0 >> 8, rhalf = (p0 >> 7) & 1;
    char* outb = Ag + (size_t)(fb * 256 + tile) * 131072;
#pragma unroll
    for (int it = 0; it < 8; ++it) {
        int id = tid + it * 512;              // 0..4095 16B chunks
        int pl = id >> 11, kg = (id >> 7) & 15, r2 = id & 127;
        i32x4 vv = *(const i32x4*)&at[pl][kg][r2][0];
        *(i32x4*)&outb[(size_t)pl * 65536 + kg * 4096 + (rhalf * 128 + r2) * 16] = vv;
    }
}

// ---------------- convA: keypoint descriptors -> i8 hi/lo planes, 32-col tiles ----------------
__global__ __launch_bounds__(256)
void convA_kernel(const float* __restrict__ kdesc, char* __restrict__ Bg) {
    __shared__ char bt[2][16][32][16];        // 16 KB
    __shared__ float scr[8][32];
    const int bid = blockIdx.x;               // 0..63
    const int b   = bid >> 5;
    const int nt  = bid & 31;
    const int n0  = nt * 32;
    const int tid = threadIdx.x;
    const int col = tid & 31;
    const int q   = tid >> 5;                 // 0..7 -> channels q*31..q*31+30

    const float* kp = kdesc + (size_t)(2 * b + 1) * CC * NN + n0 + col;
    float ss = 0.f;
    for (int i = 0; i < 31; ++i) {
        int c = q * 31 + i;
        float v = kp[(size_t)c * NN];
        ss += v * v;
    }
    scr[q][col] = ss;
    __syncthreads();
    float tot = 0.f;
#pragma unroll
    for (int k = 0; k < 8; ++k) tot += scr[k][col];
    float inv = 32768.0f / fmaxf(sqrtf(tot), 1e-12f);
    if (tid < 64) {                            // zero k-pad c=248..255
        int pl = tid >> 5, c2 = tid & 31;
        *(long*)&bt[pl][15][c2][8] = 0L;
    }
    __syncthreads();
    for (int i = 0; i < 31; ++i) {
        int c = q * 31 + i;
        float qq = fminf(fmaxf(rintf(kp[(size_t)c * NN] * inv), -32768.f), 32639.f);
        int af = (int)qq;
        int a1 = (af + 128) >> 8;
        int a0 = af - (a1 << 8);
        bt[0][c >> 4][col][c & 15] = (char)a1;
        bt[1][c >> 4][col][c & 15] = (char)a0;
    }
    __syncthreads();
    char* outb = Bg + (size_t)(b * 32 + nt) * 16384;
    const char* src = &bt[0][0][0][0];
#pragma unroll
    for (int it = 0; it < 4; ++it) {
        int id = tid + it * 256;              // 0..1023 16B chunks
        *(i32x4*)&outb[(size_t)id * 16] = *(const i32x4*)&src[(size_t)id * 16];
    }
}

// ---------------- fused i8 MFMA GEMM: frag-pipelined, A ring in LDS, B-hi regs, B-lo LDS ----
// Block: 4 waves, BN=256 (64 n per wave), BM=1024 (16 mt of 64 rows), 128 slices.
// LDS: A ring 3 x 4096 [pl2][kgl2][row64][16] at 0;  B0 (lo plane) 64 KB at 12288.
__global__ __launch_bounds__(256, 2)
void gemm_kernel(const char* __restrict__ Ag, const char* __restrict__ Bg,
                 float* __restrict__ partials) {
    extern __shared__ char lds[];
    const int B0OFF = 12288;

    const int bid  = blockIdx.x;              // 0..511
    const int xcd  = bid & 7;
    const int rest = bid >> 3;                // 0..63
    const int nchunk = rest & 3;
    const int pid  = xcd + 8 * (rest >> 2);   // 0..127 : A-panel sharers -> same XCD
    const int b      = pid >> 6;
    const int mchunk = pid & 63;              // BM = 1024

    const int tid  = threadIdx.x;
    const int lane = tid & 63;
    const int w    = tid >> 6;                // 0..3
    const int lrow = lane & 31;
    const int lhi  = lane >> 5;

    const char* atile0 = Ag + ((size_t)b * 256 + mchunk * 4) * 131072;  // 4 tiles of 256 rows
    const char* bbase  = Bg + (size_t)(b * 32 + nchunk * 8) * 16384;    // 8 n-tiles

    // ---- stage B0 (lo plane of 8 tiles, 64 KB) ----
#pragma unroll
    for (int i = 0; i < 16; ++i) {
        int c = w * 16 + i;                    // 0..63 1KB chunks
        int t = c >> 3, j = c & 7;
        const char* src = bbase + t * 16384 + 8192 + j * 1024 + lane * 16;
        __builtin_amdgcn_global_load_lds(
            (const __attribute__((address_space(1))) void*)src,
            (__attribute__((address_space(3))) void*)&lds[B0OFF + t * 8192 + j * 1024], 16, 0, 0);
    }

    // ---- bc: b1 (hi plane), full K, this wave's 2 n-tiles -> 64 regs ----
    i32x4 bc[8][2];
#pragma unroll
    for (int ks = 0; ks < 8; ++ks)
#pragma unroll
        for (int bp = 0; bp < 2; ++bp)
            bc[ks][bp] = *(const i32x4*)(bbase + (size_t)(2 * w + bp) * 16384
                                         + (ks * 2 + lhi) * 512 + lrow * 16);

    // staging: wave w owns chunk (pl=w>>1, kgl=w&1) of each slice
    auto ISSUE = [&](int s, int slotOff) {
        const int mtn = s >> 3, ksn = s & 7;
        const char* src = atile0 + (size_t)(mtn >> 2) * 131072 + (w >> 1) * 65536
                        + (ksn * 2 + (w & 1)) * 4096 + ((mtn & 3) * 64 + lane) * 16;
        char* dst = &lds[slotOff + (w >> 1) * 2048 + (w & 1) * 1024];
        __builtin_amdgcn_global_load_lds(
            (const __attribute__((address_space(1))) void*)src,
            (__attribute__((address_space(3))) void*)dst, 16, 0, 0);
    };

    i32x16 accH[2][2], accX[2][2];
#pragma unroll
    for (int ap = 0; ap < 2; ++ap)
#pragma unroll
        for (int bp = 0; bp < 2; ++bp) { accH[ap][bp] = (i32x16)(0); accX[ap][bp] = (i32x16)(0); }
    float rm[2], rz[2], rsu[2], rsv[2];
#pragma unroll
    for (int bp = 0; bp < 2; ++bp) { rm[bp] = -INFINITY; rz[bp] = 0.f; rsu[bp] = 0.f; rsv[bp] = 0.f; }

    const float S2 = 100.0f * 1.4426950408889634f / 1073741824.0f;  // 100*log2e/2^30
    const float cH = 65536.0f * S2;
    const float cX = 256.0f * S2;

    // aF ping-pong: frags of slice s live in buffer s&1
    i32x4 aF[2][2][2];   // [pp][pl][ap]

    auto RDA = [&](int pp, int slotOff) {
#pragma unroll
        for (int pl = 0; pl < 2; ++pl)
#pragma unroll
            for (int ap = 0; ap < 2; ++ap)
                aF[pp][pl][ap] = *(const i32x4*)&lds[slotOff + pl * 2048 + lhi * 1024
                                                     + (ap * 32 + lrow) * 16];
    };

    ISSUE(0, 0);
    ISSUE(1, 4096);
    ISSUE(2, 8192);
    asm volatile("s_waitcnt vmcnt(2)" ::: "memory");   // B0 + bc + A(0) complete
    asm volatile("s_barrier" ::: "memory");
    RDA(0, 0);                                          // frags(0) -> buf 0

    int slotW = 0, slotR = 4096;   // iter s: ISSUE(s+3)->slotW (=s%3), RDA(s+1)<-slotR (=(s+1)%3)

    for (int mt = 0; mt < 16; ++mt) {
#pragma unroll
        for (int ks = 0; ks < 8; ++ks) {
            const int s = mt * 8 + ks;
            const int pp = ks & 1;

            // b0F for current slice — B0 is resident, read before the wait (latency hidden)
            i32x4 b0F[2];
#pragma unroll
            for (int bp = 0; bp < 2; ++bp)
                b0F[bp] = *(const i32x4*)&lds[B0OFF + (2 * w + bp) * 8192
                                              + (ks * 2 + lhi) * 512 + lrow * 16];

            if (s < 126)       asm volatile("s_waitcnt vmcnt(1)" ::: "memory");
            else if (s == 126) asm volatile("s_waitcnt vmcnt(0)" ::: "memory");
            if (s < 127) {
                asm volatile("s_barrier" ::: "memory");
                if (s + 3 <= 127) ISSUE(s + 3, slotW);
                RDA(pp ^ 1, slotR);            // frags(s+1): consumed after next barrier
            }

            __builtin_amdgcn_s_setprio(1);
            // reg-resident operands first (no lgkm dependency on this iter's reads)
#pragma unroll
            for (int ap = 0; ap < 2; ++ap)
#pragma unroll
                for (int bp = 0; bp < 2; ++bp) {
                    accH[ap][bp] = __builtin_amdgcn_mfma_i32_32x32x32_i8(aF[pp][0][ap], bc[ks][bp], accH[ap][bp], 0, 0, 0);
                    accX[ap][bp] = __builtin_amdgcn_mfma_i32_32x32x32_i8(aF[pp][1][ap], bc[ks][bp], accX[ap][bp], 0, 0, 0);
                }
            // b0F-consuming MFMAs last (b0F issued well before the barrier)
#pragma unroll
            for (int ap = 0; ap < 2; ++ap)
#pragma unroll
                for (int bp = 0; bp < 2; ++bp)
                    accX[ap][bp] = __builtin_amdgcn_mfma_i32_32x32x32_i8(aF[pp][0][ap], b0F[bp], accX[ap][bp], 0, 0, 0);
            __builtin_amdgcn_s_setprio(0);

            slotW = (slotW == 8192) ? 0 : slotW + 4096;
            slotR = (slotR == 8192) ? 0 : slotR + 4096;

            if (ks == 7) {
                // ---- epilogue for m-tile mt (64 rows x this wave's 64 n) ----
                const int mbase = mchunk * 1024 + mt * 64;
                const float ub0 = (float)((mbase & 255) + 4 * lhi);
                const float ub1 = ub0 + 32.0f;
                const float vcoord = (float)(mbase >> 8);
#pragma unroll
                for (int bp = 0; bp < 2; ++bp) {
                    int hm = accH[0][bp][0];
#pragma unroll
                    for (int ap = 0; ap < 2; ++ap)
#pragma unroll
                        for (int r = 0; r < 16; ++r) {
                            int h = accH[ap][bp][r];
                            hm = (h > hm) ? h : hm;
                        }
                    const float bx = (float)hm * cH;
                    float tz0 = 0.f, tz1 = 0.f, tsur = 0.f;
#pragma unroll
                    for (int ap = 0; ap < 2; ++ap)
#pragma unroll
                        for (int r = 0; r < 16; ++r) {
                            int dH = accH[ap][bp][r] - hm;         // exact
                            float e = fexp2(fmaf((float)dH, cH, (float)accX[ap][bp][r] * cX));
                            if (ap == 0) tz0 += e; else tz1 += e;
                            tsur = fmaf(e, (float)((r & 3) + 8 * (r >> 2)), tsur);
                        }
                    float tzz = tz0 + tz1;
                    float tsu = fmaf(ub0, tz0, fmaf(ub1, tz1, tsur));
                    float tsv = vcoord * tzz;
                    float nm = fmaxf(rm[bp], bx);
                    float f1 = fexp2(rm[bp] - nm), f2 = fexp2(bx - nm);
                    rz[bp]  = rz[bp]  * f1 + tzz * f2;
                    rsu[bp] = rsu[bp] * f1 + tsu * f2;
                    rsv[bp] = rsv[bp] * f1 + tsv * f2;
                    rm[bp]  = nm;
#pragma unroll
                    for (int ap = 0; ap < 2; ++ap) { accH[ap][bp] = (i32x16)(0); accX[ap][bp] = (i32x16)(0); }
                }
            }
        }
    }

    // ---- merge lane <-> lane+32 (same column, other row half), write partials ----
#pragma unroll
    for (int bp = 0; bp < 2; ++bp) {
        float m2  = __shfl_xor(rm[bp], 32, 64);
        float z2  = __shfl_xor(rz[bp], 32, 64);
        float su2 = __shfl_xor(rsu[bp], 32, 64);
        float sv2 = __shfl_xor(rsv[bp], 32, 64);
        float nm = fmaxf(rm[bp], m2);
        float f1 = fexp2(rm[bp] - nm), f2 = fexp2(m2 - nm);
        rz[bp]  = rz[bp]  * f1 + z2  * f2;
        rsu[bp] = rsu[bp] * f1 + su2 * f2;
        rsv[bp] = rsv[bp] * f1 + sv2 * f2;
        rm[bp]  = nm;
    }
    if (lane < 32) {
#pragma unroll
        for (int bp = 0; bp < 2; ++bp) {
            int n = nchunk * 256 + w * 64 + bp * 32 + lrow;
            size_t idxp = ((size_t)b * NN + n) * 64 + mchunk;
            ((float4*)partials)[idxp] = make_float4(rm[bp], rz[bp], rsu[bp], rsv[bp]);
        }
    }
}

// ---------------- combine: one wave per (b,n) row, 64 partials each ----------------
__global__ __launch_bounds__(256)
void combine_kernel(const float* __restrict__ partials,
                    const float* __restrict__ kscores,
                    const float* __restrict__ times,
                    float* __restrict__ out) {
    const int wg   = blockIdx.x * 4 + (threadIdx.x >> 6);  // 0..2047 = (b, n)
    const int lane = threadIdx.x & 63;
    const int b = wg >> 10, n = wg & 1023;
    const float4* pp = (const float4*)partials + (size_t)wg * 64;

    float4 p = pp[lane];
    float m = p.x, z = p.y, su = p.z, sv = p.w;
#pragma unroll
    for (int mask = 32; mask >= 1; mask >>= 1) {
        float m2  = __shfl_xor(m, mask, 64);
        float z2  = __shfl_xor(z, mask, 64);
        float su2 = __shfl_xor(su, mask, 64);
        float sv2 = __shfl_xor(sv, mask, 64);
        float nm = fmaxf(m, m2);
        float f1 = fexp2(m - nm), f2 = fexp2(m2 - nm);
        z = z * f1 + z2 * f2; su = su * f1 + su2 * f2; sv = sv * f1 + sv2 * f2; m = nm;
    }

    if (lane == 0) {
        float u = su / z, v = sv / z;
        out[(size_t)wg * 2 + 0] = u;
        out[(size_t)wg * 2 + 1] = v;
        out[4096 + wg] = kscores[(size_t)(2 * b + 1) * NN + n];
        if (wg == 0) { out[6144] = 1.0f; out[6145] = 3.0f; }

        const float* timg = times + (size_t)(2 * b) * MM;
        float u0 = fminf(fmaxf(floorf(u), 0.f), 255.f);
        float v0 = fminf(fmaxf(floorf(v), 0.f), 255.f);
        float u1 = fminf(u0 + 1.f, 255.f);
        float v1 = fminf(v0 + 1.f, 255.f);
        float au = u - u0, av = v - v0;
        int u0i = (int)u0, u1i = (int)u1, v0i = (int)v0, v1i = (int)v1;
        float t00 = timg[v0i * 256 + u0i], t01 = timg[v0i * 256 + u1i];
        float t10 = timg[v1i * 256 + u0i], t11 = timg[v1i * 256 + u1i];
        float t = t00 * (1.f - au) * (1.f - av) + t01 * au * (1.f - av)
                + t10 * (1.f - au) * av + t11 * au * av;
        out[6146 + wg] = t;
    }
}

extern "C" void kernel_launch(void* const* d_in, const int* in_sizes, int n_in,
                              void* d_out, int out_size, void* d_ws, size_t ws_size,
                              hipStream_t stream) {
    const float* kscores = (const float*)d_in[0];
    const float* kdesc   = (const float*)d_in[1];
    const float* dense   = (const float*)d_in[2];
    const float* times   = (const float*)d_in[3];
    float* out = (float*)d_out;

    char* Ag = (char*)d_ws;                                   // 67,108,864 B
    char* Bg = Ag + (size_t)2 * 256 * 131072;                 //  1,048,576 B
    float* partials = (float*)(Bg + (size_t)2 * 32 * 16384);  //  2,097,152 B

    hipFuncSetAttribute((const void*)gemm_kernel,
                        hipFuncAttributeMaxDynamicSharedMemorySize, 77824);

    hipLaunchKernelGGL(convB_kernel,   dim3(1024), dim3(512), 0, stream, dense, Ag);
    hipLaunchKernelGGL(convA_kernel,   dim3(64),   dim3(256), 0, stream, kdesc, Bg);
    hipLaunchKernelGGL(gemm_kernel,    dim3(512),  dim3(256), 77824, stream, Ag, Bg, partials);
    hipLaunchKernelGGL(combine_kernel, dim3(512),  dim3(256), 0, stream, partials, kscores, times, out);
}